// Round 1
// baseline (856.367 us; speedup 1.0000x reference)
//
#include <hip/hip_runtime.h>

typedef __attribute__((ext_vector_type(8))) short short8;
typedef __attribute__((ext_vector_type(4))) float f32x4;

#define TT 2048
#define DD 512
#define NB 192      // 3 gates * 64 h-channels
#define BT 64       // t-chunk

__device__ __forceinline__ unsigned short f2bf(float f) {
  unsigned int u = __float_as_uint(f);
  u += 0x7FFFu + ((u >> 16) & 1u);
  return (unsigned short)(u >> 16);
}

// Transpose+convert W[512][1536] fp32 -> Wt[dir][1536 cols][512 k] bf16 in ws
__global__ void wtrans_kernel(const float* __restrict__ Wf,
                              const float* __restrict__ Wb,
                              unsigned short* __restrict__ wt) {
  __shared__ float tile[32][33];
  int bid = blockIdx.x;            // 2 * 16 * 48 = 1536
  int d   = bid / 768;
  int rem = bid - d * 768;
  int kt = rem & 15;               // 16 k-tiles
  int ct = rem >> 4;               // 48 col-tiles
  const float* W = d ? Wb : Wf;
  int k0 = kt * 32, c0 = ct * 32;
  int r = threadIdx.x >> 5, c = threadIdx.x & 31;
#pragma unroll
  for (int i = 0; i < 4; i++)
    tile[r + 8*i][c] = W[(size_t)(k0 + r + 8*i) * 1536 + c0 + c];
  __syncthreads();
  unsigned short* outp = wt + ((size_t)d * 1536 + c0) * 512 + k0;
#pragma unroll
  for (int i = 0; i < 4; i++)
    outp[(size_t)(r + 8*i) * 512 + c] = f2bf(tile[c][r + 8*i]);
}

// One block = (dir, b, 64-h tile). Sequential over T in 64-t chunks:
// chunk-GEMM (bf16 MFMA) -> activations -> in-register fo-pool scan -> store.
__global__ __launch_bounds__(256, 2)
void qrnn_kernel(const float* __restrict__ x,
                 const float* __restrict__ bf_, const float* __restrict__ bb_,
                 const unsigned short* __restrict__ wt,
                 float* __restrict__ out) {
  __shared__ __align__(16) unsigned short sA[64 * 64];  // bf16 bits, XOR-swizzled
  __shared__ float sG[64 * 193];                        // padded g tile
  __shared__ float sBias[NB];

  const int tid  = threadIdx.x;
  const int lane = tid & 63;
  const int wv   = tid >> 6;

  // XCD-aware swizzle: 16 blocks sharing batch b land on one XCD (round-robin p&7)
  int p = blockIdx.x;
  int xcd = p & 7, slot = p >> 3;
  int b   = xcd * 4 + (slot >> 4);
  int v   = slot & 15;
  int dir = v >> 3, ht = v & 7;
  int h0  = ht * 64;

  if (tid < NB) {
    const float* bsrc = dir ? bb_ : bf_;
    sBias[tid] = bsrc[((tid >> 6) << 9) + h0 + (tid & 63)];
  }

  const float* xb = x + (size_t)b * TT * DD;
  const unsigned short* wtd = wt + (size_t)dir * 1536 * 512;

  // B-fragment global element offsets: n = 48*wv + 16*j + (lane&15); k-contig bf16
  size_t brow[3];
#pragma unroll
  for (int j = 0; j < 3; j++) {
    int n = 48 * wv + 16 * j + (lane & 15);
    brow[j] = (size_t)(((n >> 6) << 9) + h0 + (n & 63)) * 512 + 8 * (lane >> 4);
  }

  // A-fragment LDS byte offsets (swizzled)
  int a_off[2][4];
#pragma unroll
  for (int kk = 0; kk < 2; kk++)
#pragma unroll
    for (int m = 0; m < 4; m++) {
      int row = 16 * m + (lane & 15);
      a_off[kk][m] = row * 128 + ((64 * kk + 16 * (lane >> 4)) ^ ((row & 7) << 4));
    }

  // staging mapping: quad q = tid + 256*i -> row q>>4, 4-float group q&15
  int s_trow[4], s_kq[4], s_woff[4];
#pragma unroll
  for (int i = 0; i < 4; i++) {
    int q = tid + 256 * i;
    s_trow[i] = q >> 4;
    s_kq[i]   = q & 15;
    s_woff[i] = s_trow[i] * 128 + ((8 * s_kq[i]) ^ ((s_trow[i] & 7) << 4));
  }

  float c = 0.f;  // recurrence state (wave 0, lane = h')
  f32x4 acc[4][3];

  for (int t0 = 0; t0 < TT; t0 += BT) {
#pragma unroll
    for (int m = 0; m < 4; m++)
#pragma unroll
      for (int j = 0; j < 3; j++)
        acc[m][j] = f32x4{0.f, 0.f, 0.f, 0.f};

    // prologue: issue global loads for ks=0
    float4 vv[4];
#pragma unroll
    for (int i = 0; i < 4; i++)
      vv[i] = *(const float4*)(xb + (size_t)(t0 + s_trow[i]) * DD + 4 * s_kq[i]);

#pragma unroll
    for (int ks = 0; ks < 8; ks++) {
      __syncthreads();  // previous k-step's LDS reads complete
#pragma unroll
      for (int i = 0; i < 4; i++) {
        ushort4 u;
        u.x = f2bf(vv[i].x); u.y = f2bf(vv[i].y);
        u.z = f2bf(vv[i].z); u.w = f2bf(vv[i].w);
        *(ushort4*)((char*)sA + s_woff[i]) = u;
      }
      if (ks < 7) {  // issue next k-step's loads early; latency hides under MFMA
        int k0n = (ks + 1) * 64;
#pragma unroll
        for (int i = 0; i < 4; i++)
          vv[i] = *(const float4*)(xb + (size_t)(t0 + s_trow[i]) * DD + k0n + 4 * s_kq[i]);
      }
      __syncthreads();  // sA ready
      const char* sAb = (const char*)sA;
      int k0 = ks * 64;
#pragma unroll
      for (int kk = 0; kk < 2; kk++) {
        short8 bfr[3];
#pragma unroll
        for (int j = 0; j < 3; j++)
          bfr[j] = *(const short8*)(wtd + brow[j] + k0 + 32 * kk);
#pragma unroll
        for (int m = 0; m < 4; m++) {
          short8 afr = *(const short8*)(sAb + a_off[kk][m]);
#pragma unroll
          for (int j = 0; j < 3; j++)
            acc[m][j] = __builtin_amdgcn_mfma_f32_16x16x32_bf16(afr, bfr[j], acc[m][j], 0, 0, 0);
        }
      }
    }

    // epilogue: acc -> sG (C/D layout: col = lane&15, row = 4*(lane>>4)+r)
#pragma unroll
    for (int m = 0; m < 4; m++)
#pragma unroll
      for (int j = 0; j < 3; j++) {
        int col   = 48 * wv + 16 * j + (lane & 15);
        int rbase = 16 * m + 4 * (lane >> 4);
#pragma unroll
        for (int r = 0; r < 4; r++)
          sG[(rbase + r) * 193 + col] = acc[m][j][r];
      }
    __syncthreads();

    // activations: all 4 waves, gate is wave-uniform by construction
    for (int idx = tid; idx < 64 * NB; idx += 256) {
      int t = idx / NB;
      int n = idx - t * NB;
      float g = sG[t * 193 + n] + sBias[n];
      float res;
      if (n < 64) {                       // z: tanh
        float e = __expf(2.f * g);
        res = 1.f - 2.f / (e + 1.f);
      } else {                            // f,o: sigmoid
        res = 1.f / (1.f + __expf(-g));
      }
      sG[t * 193 + n] = res;
    }
    __syncthreads();

    // fo-pool recurrence + output (wave 0; c persists in registers)
    if (tid < 64) {
      float* og = out + ((size_t)(b * TT + t0)) * 1024 + (dir << 9) + h0 + tid;
      float cc = c;
#pragma unroll 8
      for (int t = 0; t < BT; t++) {
        float z = sG[t * 193 + tid];
        float f = sG[t * 193 + 64 + tid];
        float o = sG[t * 193 + 128 + tid];
        cc = z + f * (cc - z);            // f*c + (1-f)*z
        og[(size_t)t << 10] = o * cc;
      }
      c = cc;
    }
  }
}

extern "C" void kernel_launch(void* const* d_in, const int* in_sizes, int n_in,
                              void* d_out, int out_size, void* d_ws, size_t ws_size,
                              hipStream_t stream) {
  const float* x   = (const float*)d_in[0];
  const float* W_f = (const float*)d_in[1];
  const float* b_f = (const float*)d_in[2];
  const float* W_b = (const float*)d_in[3];
  const float* b_b = (const float*)d_in[4];
  float* out = (float*)d_out;
  unsigned short* wt = (unsigned short*)d_ws;  // [2][1536][512] bf16 = 3 MiB

  wtrans_kernel<<<1536, 256, 0, stream>>>(W_f, W_b, wt);
  qrnn_kernel<<<512, 256, 0, stream>>>(x, b_f, b_b, wt, out);
}

// Round 2
// 509.951 us; speedup vs baseline: 1.6793x; 1.6793x over previous
//
#include <hip/hip_runtime.h>
#include <hip/hip_fp16.h>

typedef __attribute__((ext_vector_type(8))) short short8;
typedef __attribute__((ext_vector_type(4))) float f32x4;

#define TT 2048
#define DD 512

__device__ __forceinline__ unsigned short f2bf(float f) {
  unsigned int u = __float_as_uint(f);
  u += 0x7FFFu + ((u >> 16) & 1u);
  return (unsigned short)(u >> 16);
}
__device__ __forceinline__ unsigned short f2h(float f) {
  return __half_as_ushort(__float2half(f));
}
__device__ __forceinline__ float h2f(unsigned short u) {
  return __half2float(__ushort_as_half(u));
}
__device__ __forceinline__ void gload16(const void* g, void* l) {
  __builtin_amdgcn_global_load_lds((const __attribute__((address_space(1))) void*)g,
                                   (__attribute__((address_space(3))) void*)l, 16, 0, 0);
}

// ---------- prep kernels ----------

// x fp32 [65536*512] -> bf16
__global__ void xconv_kernel(const float* __restrict__ x, unsigned short* __restrict__ xbf) {
  int i = blockIdx.x * 256 + threadIdx.x;   // 4,194,304 threads, 8 elems each
  const float4* p = (const float4*)x + (size_t)i * 2;
  float4 a = p[0], b = p[1];
  short8 o;
  o[0] = f2bf(a.x); o[1] = f2bf(a.y); o[2] = f2bf(a.z); o[3] = f2bf(a.w);
  o[4] = f2bf(b.x); o[5] = f2bf(b.y); o[6] = f2bf(b.z); o[7] = f2bf(b.w);
  *((short8*)xbf + i) = o;
}

// W[512][1536] fp32 -> Wt[dir][1536 n][512 k] bf16
__global__ void wtrans_kernel(const float* __restrict__ Wf,
                              const float* __restrict__ Wb,
                              unsigned short* __restrict__ wt) {
  __shared__ float tile[32][33];
  int bid = blockIdx.x;            // 2 * 16 * 48
  int d   = bid / 768;
  int rem = bid - d * 768;
  int kt = rem & 15;
  int ct = rem >> 4;
  const float* W = d ? Wb : Wf;
  int k0 = kt * 32, c0 = ct * 32;
  int r = threadIdx.x >> 5, c = threadIdx.x & 31;
#pragma unroll
  for (int i = 0; i < 4; i++)
    tile[r + 8*i][c] = W[(size_t)(k0 + r + 8*i) * 1536 + c0 + c];
  __syncthreads();
  unsigned short* outp = wt + ((size_t)d * 1536 + c0) * 512 + k0;
#pragma unroll
  for (int i = 0; i < 4; i++)
    outp[(size_t)(r + 8*i) * 512 + c] = f2bf(tile[c][r + 8*i]);
}

__global__ void cbias_kernel(const float* __restrict__ bf_, const float* __restrict__ bb_,
                             float* __restrict__ cb) {
  int n = blockIdx.x * 256 + threadIdx.x;   // 3072
  cb[n] = (n < 1536) ? bf_[n] : bb_[n - 1536];
}

// ---------- GEMM + activation ----------
// C[m][n] = sum_k xbf[m][k] * wt[n][k] + bias[n], act per gate, store fp16 to G.
// 128x128 tile, BK=64, 4 waves (2x2), m97 structure with swizzled-source global_load_lds.
__global__ __launch_bounds__(256, 3)
void gemm_act_kernel(const unsigned short* __restrict__ xbf,
                     const unsigned short* __restrict__ wt,
                     const float* __restrict__ cbias,
                     unsigned short* __restrict__ G,
                     int ncb, int gstride) {
  __shared__ __align__(16) char smem[32768];   // sA 16K | sB 16K; reused as epi tile

  int bid = blockIdx.x;
  int cpx = gridDim.x >> 3;                    // grid % 8 == 0
  int bid2 = (bid & 7) * cpx + (bid >> 3);
  int bm = bid2 / ncb, bn = bid2 - bm * ncb;
  size_t m0 = (size_t)bm * 128;
  int n0 = bn * 128;

  int tid = threadIdx.x, lane = tid & 63, wv = tid >> 6;
  int wm = wv >> 1, wn = wv & 1;

  // staging source mapping: LDS linear pos p = tid*16 + i*4096 -> row=p>>7, kb=p&127
  // source kb' = kb ^ ((row&7)<<4)  (inverse-swizzled source, linear LDS dest)
  int srow = tid >> 3;
  int skb  = (tid * 16) & 127;
  int sws  = skb ^ ((srow & 7) << 4);
  const char* aSrc = (const char*)xbf + m0 * 1024 + (size_t)srow * 1024 + sws;
  const char* bSrc = (const char*)wt + (size_t)n0 * 1024 + (size_t)srow * 1024 + sws;

  // fragment read offsets (swizzled)
  int aoff[2][4], boff[2][4];
#pragma unroll
  for (int kk = 0; kk < 2; kk++)
#pragma unroll
    for (int i = 0; i < 4; i++) {
      int rowA = wm * 64 + i * 16 + (lane & 15);
      int rowB = wn * 64 + i * 16 + (lane & 15);
      int kby  = kk * 64 + (lane >> 4) * 16;
      aoff[kk][i] = rowA * 128 + (kby ^ ((rowA & 7) << 4));
      boff[kk][i] = 16384 + rowB * 128 + (kby ^ ((rowB & 7) << 4));
    }

  f32x4 acc[4][4];
#pragma unroll
  for (int i = 0; i < 4; i++)
#pragma unroll
    for (int j = 0; j < 4; j++)
      acc[i][j] = f32x4{0.f, 0.f, 0.f, 0.f};

  for (int kt = 0; kt < 8; ++kt) {
    if (kt) __syncthreads();
    int k0b = kt * 128;  // 64 k * 2B
#pragma unroll
    for (int i = 0; i < 4; i++)
      gload16(aSrc + i * 32768 + k0b, smem + tid * 16 + i * 4096);
#pragma unroll
    for (int i = 0; i < 4; i++)
      gload16(bSrc + i * 32768 + k0b, smem + 16384 + tid * 16 + i * 4096);
    __syncthreads();
#pragma unroll
    for (int kk = 0; kk < 2; kk++) {
      short8 av[4], bv[4];
#pragma unroll
      for (int i = 0; i < 4; i++) {
        av[i] = *(const short8*)(smem + aoff[kk][i]);
        bv[i] = *(const short8*)(smem + boff[kk][i]);
      }
#pragma unroll
      for (int mm = 0; mm < 4; mm++)
#pragma unroll
        for (int jj = 0; jj < 4; jj++)
          acc[mm][jj] = __builtin_amdgcn_mfma_f32_16x16x32_bf16(av[mm], bv[jj], acc[mm][jj], 0, 0, 0);
    }
  }

  __syncthreads();
  // epilogue: bias + activation -> fp16 -> LDS transpose tile -> coalesced store
  int g3 = (n0 % 1536) >> 9;   // 0=z(tanh) 1=f 2=o (sigmoid)
  float cb[4];
#pragma unroll
  for (int jj = 0; jj < 4; jj++)
    cb[jj] = cbias[n0 + wn * 64 + jj * 16 + (lane & 15)];

#pragma unroll
  for (int mm = 0; mm < 4; mm++)
#pragma unroll
    for (int jj = 0; jj < 4; jj++) {
      int colb = (wn * 64 + jj * 16 + (lane & 15)) * 2;
#pragma unroll
      for (int r = 0; r < 4; r++) {
        int row = wm * 64 + mm * 16 + (lane >> 4) * 4 + r;
        float v = acc[mm][jj][r] + cb[jj];
        float a;
        if (g3 == 0) { float e = __expf(2.f * v); a = 1.f - 2.f / (e + 1.f); }
        else         { a = 1.f / (1.f + __expf(-v)); }
        *(unsigned short*)(smem + row * 256 + (colb ^ ((row & 12) << 2))) = f2h(a);
      }
    }
  __syncthreads();
#pragma unroll
  for (int ps = 0; ps < 8; ps++) {
    int row = ps * 16 + (tid >> 4);
    int cb2 = ((tid & 15) * 16) ^ ((row & 12) << 2);
    short8 vv = *(const short8*)(smem + row * 256 + cb2);
    *(short8*)((char*)G + ((m0 + row) * gstride + n0) * 2 + (tid & 15) * 16) = vv;
  }
}

// ---------- chunked scan ----------
// G cols per dir: [z | f | o] each 512. C channels = ndirs*512. 16 chunks of 128 t.

__global__ void scan_carry_kernel(const unsigned short* __restrict__ G,
                                  float2* __restrict__ carry, int gstride, int C) {
  int C4 = C >> 8;
  int bid = blockIdx.x;
  int b = bid / (16 * C4); int rem = bid - b * (16 * C4);
  int ch = rem / C4; int grp = rem - ch * C4;
  int q = grp * 256 + threadIdx.x;
  int dir = q >> 9, h = q & 511;
  size_t row0 = (size_t)b * TT + ch * 128;
  const unsigned short* p = G + row0 * gstride + dir * 1536 + h;
  float A = 1.f, Bv = 0.f;
#pragma unroll 4
  for (int t = 0; t < 128; ++t) {
    float z = h2f(p[0]);
    float f = h2f(p[512]);
    Bv = f * Bv + (1.f - f) * z;
    A *= f;
    p += gstride;
  }
  carry[(size_t)(b * 16 + ch) * C + q] = float2{A, Bv};
}

__global__ void scan_combine_kernel(const float2* __restrict__ carry,
                                    float* __restrict__ cin, int C) {
  int gid = blockIdx.x * 256 + threadIdx.x;  // 32*C
  int b = gid / C, q = gid - b * C;
  float c = 0.f;
#pragma unroll
  for (int ch = 0; ch < 16; ++ch) {
    size_t idx = (size_t)(b * 16 + ch) * C + q;
    cin[idx] = c;
    float2 ab = carry[idx];
    c = ab.x * c + ab.y;
  }
}

__global__ void scan_final_kernel(const unsigned short* __restrict__ G,
                                  const float* __restrict__ cin,
                                  float* __restrict__ out,
                                  int gstride, int C, int dbase) {
  int C4 = C >> 8;
  int bid = blockIdx.x;
  int b = bid / (16 * C4); int rem = bid - b * (16 * C4);
  int ch = rem / C4; int grp = rem - ch * C4;
  int q = grp * 256 + threadIdx.x;
  int dir = q >> 9, h = q & 511;
  size_t row0 = (size_t)b * TT + ch * 128;
  const unsigned short* p = G + row0 * gstride + dir * 1536 + h;
  float* po = out + row0 * 1024 + (size_t)(dbase + dir) * 512 + h;
  float c = cin[(size_t)(b * 16 + ch) * C + q];
#pragma unroll 4
  for (int t = 0; t < 128; ++t) {
    float z = h2f(p[0]);
    float f = h2f(p[512]);
    float o = h2f(p[1024]);
    c = f * c + (1.f - f) * z;
    *po = o * c;
    p += gstride; po += 1024;
  }
}

// ---------- round-1 fused fallback (small-ws path) ----------
#define NB 192
#define BT 64
__global__ __launch_bounds__(256, 2)
void qrnn_kernel(const float* __restrict__ x,
                 const float* __restrict__ bf_, const float* __restrict__ bb_,
                 const unsigned short* __restrict__ wt,
                 float* __restrict__ out) {
  __shared__ __align__(16) unsigned short sA[64 * 64];
  __shared__ float sG[64 * 193];
  __shared__ float sBias[NB];
  const int tid  = threadIdx.x;
  const int lane = tid & 63;
  const int wv   = tid >> 6;
  int p = blockIdx.x;
  int xcd = p & 7, slot = p >> 3;
  int b   = xcd * 4 + (slot >> 4);
  int v   = slot & 15;
  int dir = v >> 3, ht = v & 7;
  int h0  = ht * 64;
  if (tid < NB) {
    const float* bsrc = dir ? bb_ : bf_;
    sBias[tid] = bsrc[((tid >> 6) << 9) + h0 + (tid & 63)];
  }
  const float* xb = x + (size_t)b * TT * DD;
  const unsigned short* wtd = wt + (size_t)dir * 1536 * 512;
  size_t brow[3];
#pragma unroll
  for (int j = 0; j < 3; j++) {
    int n = 48 * wv + 16 * j + (lane & 15);
    brow[j] = (size_t)(((n >> 6) << 9) + h0 + (n & 63)) * 512 + 8 * (lane >> 4);
  }
  int a_off[2][4];
#pragma unroll
  for (int kk = 0; kk < 2; kk++)
#pragma unroll
    for (int m = 0; m < 4; m++) {
      int row = 16 * m + (lane & 15);
      a_off[kk][m] = row * 128 + ((64 * kk + 16 * (lane >> 4)) ^ ((row & 7) << 4));
    }
  int s_trow[4], s_kq[4], s_woff[4];
#pragma unroll
  for (int i = 0; i < 4; i++) {
    int q = tid + 256 * i;
    s_trow[i] = q >> 4;
    s_kq[i]   = q & 15;
    s_woff[i] = s_trow[i] * 128 + ((8 * s_kq[i]) ^ ((s_trow[i] & 7) << 4));
  }
  float c = 0.f;
  f32x4 acc[4][3];
  for (int t0 = 0; t0 < TT; t0 += BT) {
#pragma unroll
    for (int m = 0; m < 4; m++)
#pragma unroll
      for (int j = 0; j < 3; j++)
        acc[m][j] = f32x4{0.f, 0.f, 0.f, 0.f};
    float4 vv[4];
#pragma unroll
    for (int i = 0; i < 4; i++)
      vv[i] = *(const float4*)(xb + (size_t)(t0 + s_trow[i]) * DD + 4 * s_kq[i]);
#pragma unroll
    for (int ks = 0; ks < 8; ks++) {
      __syncthreads();
#pragma unroll
      for (int i = 0; i < 4; i++) {
        ushort4 u;
        u.x = f2bf(vv[i].x); u.y = f2bf(vv[i].y);
        u.z = f2bf(vv[i].z); u.w = f2bf(vv[i].w);
        *(ushort4*)((char*)sA + s_woff[i]) = u;
      }
      if (ks < 7) {
        int k0n = (ks + 1) * 64;
#pragma unroll
        for (int i = 0; i < 4; i++)
          vv[i] = *(const float4*)(xb + (size_t)(t0 + s_trow[i]) * DD + k0n + 4 * s_kq[i]);
      }
      __syncthreads();
      const char* sAb = (const char*)sA;
      int k0 = ks * 64;
#pragma unroll
      for (int kk = 0; kk < 2; kk++) {
        short8 bfr[3];
#pragma unroll
        for (int j = 0; j < 3; j++)
          bfr[j] = *(const short8*)(wtd + brow[j] + k0 + 32 * kk);
#pragma unroll
        for (int m = 0; m < 4; m++) {
          short8 afr = *(const short8*)(sAb + a_off[kk][m]);
#pragma unroll
          for (int j = 0; j < 3; j++)
            acc[m][j] = __builtin_amdgcn_mfma_f32_16x16x32_bf16(afr, bfr[j], acc[m][j], 0, 0, 0);
        }
      }
    }
#pragma unroll
    for (int m = 0; m < 4; m++)
#pragma unroll
      for (int j = 0; j < 3; j++) {
        int col   = 48 * wv + 16 * j + (lane & 15);
        int rbase = 16 * m + 4 * (lane >> 4);
#pragma unroll
        for (int r = 0; r < 4; r++)
          sG[(rbase + r) * 193 + col] = acc[m][j][r];
      }
    __syncthreads();
    for (int idx = tid; idx < 64 * NB; idx += 256) {
      int t = idx / NB;
      int n = idx - t * NB;
      float g = sG[t * 193 + n] + sBias[n];
      float res;
      if (n < 64) { float e = __expf(2.f * g); res = 1.f - 2.f / (e + 1.f); }
      else        { res = 1.f / (1.f + __expf(-g)); }
      sG[t * 193 + n] = res;
    }
    __syncthreads();
    if (tid < 64) {
      float* og = out + ((size_t)(b * TT + t0)) * 1024 + (dir << 9) + h0 + tid;
      float cc = c;
#pragma unroll 8
      for (int t = 0; t < BT; t++) {
        float z = sG[t * 193 + tid];
        float f = sG[t * 193 + 64 + tid];
        float o = sG[t * 193 + 128 + tid];
        cc = z + f * (cc - z);
        og[(size_t)t << 10] = o * cc;
      }
      c = cc;
    }
  }
}

extern "C" void kernel_launch(void* const* d_in, const int* in_sizes, int n_in,
                              void* d_out, int out_size, void* d_ws, size_t ws_size,
                              hipStream_t stream) {
  const float* x   = (const float*)d_in[0];
  const float* W_f = (const float*)d_in[1];
  const float* b_f = (const float*)d_in[2];
  const float* W_b = (const float*)d_in[3];
  const float* b_b = (const float*)d_in[4];
  float* out = (float*)d_out;

  char* ws = (char*)d_ws;
  const size_t OFF_WT    = 0;                    // 3,145,728
  const size_t OFF_CB    = 3145728;              // 12,288
  const size_t OFF_CARRY = 3158016;              // 4 MiB
  const size_t OFF_CIN   = 7352320;              // 2 MiB
  const size_t OFF_XBF   = 9449472;              // 64 MiB
  const size_t OFF_G     = 76558336;
  const size_t NEED_FULL = OFF_G + 402653184ull; // 479.2 MB
  const size_t NEED_DIR  = OFF_G + 201326592ull; // 277.9 MB

  unsigned short* wt   = (unsigned short*)(ws + OFF_WT);
  float* cbias         = (float*)(ws + OFF_CB);
  float2* carry        = (float2*)(ws + OFF_CARRY);
  float* cin           = (float*)(ws + OFF_CIN);
  unsigned short* xbf  = (unsigned short*)(ws + OFF_XBF);
  unsigned short* G    = (unsigned short*)(ws + OFF_G);

  if (ws_size >= NEED_FULL) {
    xconv_kernel<<<16384, 256, 0, stream>>>(x, xbf);
    wtrans_kernel<<<1536, 256, 0, stream>>>(W_f, W_b, wt);
    cbias_kernel<<<12, 256, 0, stream>>>(b_f, b_b, cbias);
    gemm_act_kernel<<<12288, 256, 0, stream>>>(xbf, wt, cbias, G, 24, 3072);
    scan_carry_kernel<<<2048, 256, 0, stream>>>(G, carry, 3072, 1024);
    scan_combine_kernel<<<128, 256, 0, stream>>>(carry, cin, 1024);
    scan_final_kernel<<<2048, 256, 0, stream>>>(G, cin, out, 3072, 1024, 0);
  } else if (ws_size >= NEED_DIR) {
    xconv_kernel<<<16384, 256, 0, stream>>>(x, xbf);
    wtrans_kernel<<<1536, 256, 0, stream>>>(W_f, W_b, wt);
    cbias_kernel<<<12, 256, 0, stream>>>(b_f, b_b, cbias);
    for (int dir = 0; dir < 2; ++dir) {
      gemm_act_kernel<<<6144, 256, 0, stream>>>(xbf, wt + (size_t)dir * 1536 * 512,
                                                cbias + dir * 1536, G, 12, 1536);
      scan_carry_kernel<<<1024, 256, 0, stream>>>(G, carry, 1536, 512);
      scan_combine_kernel<<<64, 256, 0, stream>>>(carry, cin, 512);
      scan_final_kernel<<<1024, 256, 0, stream>>>(G, cin, out, 1536, 512, dir);
    }
  } else {
    wtrans_kernel<<<1536, 256, 0, stream>>>(W_f, W_b, wt);
    qrnn_kernel<<<512, 256, 0, stream>>>(x, b_f, b_b, wt, out);
  }
}